// Round 4
// baseline (32.968 us; speedup 1.0000x reference)
//
#include <hip/hip_runtime.h>

#define POS_THR 0.7f
#define MAX_A 64

// DISCRIMINATOR ROUND: identical kernel to R3, but launched TWICE per call
// (idempotent -> still correct). dur_us delta vs R3 isolates the true kernel
// time from the fixed per-replay harness overhead.
__global__ __launch_bounds__(256) void assign_cls_kernel(
    const float4* __restrict__ bbox,      // [B, N] of (y1,x1,y2,x2)
    const float4* __restrict__ gt,        // [B, A]
    const int*    __restrict__ gt_counts, // [B]
    const int*    __restrict__ counts,    // [B]
    int*          __restrict__ out,       // [B, N]
    int N, int A)
{
    const int b = blockIdx.y;
    const int n = blockIdx.x * blockDim.x + threadIdx.x;
    const int cnt = counts[b];            // block-uniform scalar

    if ((int)(blockIdx.x * blockDim.x) >= cnt) {
        out[(size_t)b * N + n] = 0;
        return;
    }

    __shared__ float4 sgt[MAX_A];
    __shared__ float  sga[MAX_A];
    if (threadIdx.x < (unsigned)A) {
        float4 g = gt[(size_t)b * A + threadIdx.x];
        sgt[threadIdx.x] = g;
        sga[threadIdx.x] = (g.z - g.x) * (g.w - g.y);  // ga
    }
    __syncthreads();

    const int G = min(gt_counts[b], A);

    int label = 0;
    if (n < cnt) {
        const float4 bb = bbox[(size_t)b * N + n];     // coalesced dwordx4
        const float area = (bb.z - bb.x) * (bb.w - bb.y);

        #pragma unroll 4
        for (int g = 0; g < G; ++g) {
            const float4 gb = sgt[g];                  // ds_read_b128, bcast
            const float yy1 = fminf(fmaxf(bb.x, gb.x), gb.z);
            const float xx1 = fminf(fmaxf(bb.y, gb.y), gb.w);
            const float yy2 = fminf(fmaxf(bb.z, gb.x), gb.z);
            const float xx2 = fminf(fmaxf(bb.w, gb.y), gb.w);
            const float inter = (yy2 - yy1) * (xx2 - xx1);
            const float uni   = (area + sga[g]) - inter;
            label |= (inter / uni >= POS_THR);         // exact IEEE div
        }
    }
    out[(size_t)b * N + n] = label;
}

extern "C" void kernel_launch(void* const* d_in, const int* in_sizes, int n_in,
                              void* d_out, int out_size, void* d_ws, size_t ws_size,
                              hipStream_t stream) {
    const float4* bbox      = (const float4*)d_in[0];
    const float4* gt        = (const float4*)d_in[1];
    const int*    gt_counts = (const int*)d_in[2];
    const int*    counts    = (const int*)d_in[3];
    int*          out       = (int*)d_out;

    const int B = in_sizes[2];               // gt_counts has B elements
    const int A = in_sizes[1] / (4 * B);     // 64
    const int N = in_sizes[0] / (4 * B);     // 65536

    dim3 block(256, 1, 1);
    dim3 grid((N + 255) / 256, B, 1);        // 2048 blocks

    // Launch twice (idempotent): dur delta vs R3 == true kernel duration.
    assign_cls_kernel<<<grid, block, 0, stream>>>(bbox, gt, gt_counts, counts,
                                                  out, N, A);
    assign_cls_kernel<<<grid, block, 0, stream>>>(bbox, gt, gt_counts, counts,
                                                  out, N, A);
}

// Round 5
// 19.157 us; speedup vs baseline: 1.7209x; 1.7209x over previous
//
#include <hip/hip_runtime.h>

#define POS_THR 0.7f
#define MAX_A 64

// Wave-interleaved balanced kernel (specialized B==8, A<=64, N%64==0).
// Wave W (global) -> batch b = W&7, chunk nw = (q*421) mod (N/64), q = W>>3.
// Scramble spreads the active prefix (n < cnt[b]) uniformly over all CUs,
// fixing the per-CU load imbalance that capped R1-R3 at ~14 us kernel time.
// Each block's 4 waves cover 4 distinct batches at the same chunk; gt + ga
// for those batches staged in LDS (broadcast reads in the loop).
// IoU math keeps the reference's exact fp32 op order + IEEE division.
__global__ __launch_bounds__(256) void assign_cls_b8(
    const float4* __restrict__ bbox,      // [B, N]
    const float4* __restrict__ gt,        // [B, A]
    const int*    __restrict__ gt_counts, // [B]
    const int*    __restrict__ counts,    // [B]
    int*          __restrict__ out,       // [B, N]
    int N, int A, int nwMask)             // nwMask = N/64 - 1 (pow2)
{
    const int lane = threadIdx.x & 63;
    const int w    = threadIdx.x >> 6;          // wave in block: 0..3
    const int half = blockIdx.x & 1;            // which 4 batches
    const int b    = half * 4 + w;
    const int q    = blockIdx.x >> 1;           // 0..N/64-1
    const int nw   = (q * 421) & nwMask;        // bijective scramble
    const int n    = nw * 64 + lane;

    __shared__ float4 sgt[4][MAX_A];
    __shared__ float  sga[4][MAX_A];
    for (int i = threadIdx.x; i < 4 * A; i += 256) {
        const int lb = i / A, a = i - lb * A;
        float4 g = gt[(size_t)(half * 4 + lb) * A + a];
        sgt[lb][a] = g;
        sga[lb][a] = (g.z - g.x) * (g.w - g.y);   // ga
    }
    __syncthreads();

    const int cnt = counts[b];                  // wave-uniform
    const int G   = min(gt_counts[b], A);       // wave-uniform

    int label = 0;
    if (n < cnt) {
        const float4 bb = bbox[(size_t)b * N + n];   // coalesced dwordx4
        const float area = (bb.z - bb.x) * (bb.w - bb.y);

        #pragma unroll 4
        for (int g = 0; g < G; ++g) {
            const float4 gb = sgt[w][g];             // uniform addr: broadcast
            const float yy1 = fminf(fmaxf(bb.x, gb.x), gb.z);
            const float xx1 = fminf(fmaxf(bb.y, gb.y), gb.w);
            const float yy2 = fminf(fmaxf(bb.z, gb.x), gb.z);
            const float xx2 = fminf(fmaxf(bb.w, gb.y), gb.w);
            const float inter = (yy2 - yy1) * (xx2 - xx1);
            const float uni   = (area + sga[w][g]) - inter;
            label |= (inter / uni >= POS_THR);       // exact IEEE div
        }
    }
    out[(size_t)b * N + n] = label;
}

// Generic fallback (any B/A/N) — R3 structure.
__global__ __launch_bounds__(256) void assign_cls_generic(
    const float4* __restrict__ bbox, const float4* __restrict__ gt,
    const int* __restrict__ gt_counts, const int* __restrict__ counts,
    int* __restrict__ out, int N, int A)
{
    const int b = blockIdx.y;
    const int n = blockIdx.x * blockDim.x + threadIdx.x;
    if (n >= N) return;
    const int cnt = counts[b];
    const int G   = min(gt_counts[b], A);
    int label = 0;
    if (n < cnt) {
        const float4 bb = bbox[(size_t)b * N + n];
        const float area = (bb.z - bb.x) * (bb.w - bb.y);
        for (int g = 0; g < G; ++g) {
            const float4 gb = gt[(size_t)b * A + g];
            const float ga = (gb.z - gb.x) * (gb.w - gb.y);
            const float yy1 = fminf(fmaxf(bb.x, gb.x), gb.z);
            const float xx1 = fminf(fmaxf(bb.y, gb.y), gb.w);
            const float yy2 = fminf(fmaxf(bb.z, gb.x), gb.z);
            const float xx2 = fminf(fmaxf(bb.w, gb.y), gb.w);
            const float inter = (yy2 - yy1) * (xx2 - xx1);
            const float uni   = (area + ga) - inter;
            label |= (inter / uni >= POS_THR);
        }
    }
    out[(size_t)b * N + n] = label;
}

extern "C" void kernel_launch(void* const* d_in, const int* in_sizes, int n_in,
                              void* d_out, int out_size, void* d_ws, size_t ws_size,
                              hipStream_t stream) {
    const float4* bbox      = (const float4*)d_in[0];
    const float4* gt        = (const float4*)d_in[1];
    const int*    gt_counts = (const int*)d_in[2];
    const int*    counts    = (const int*)d_in[3];
    int*          out       = (int*)d_out;

    const int B = in_sizes[2];               // gt_counts has B elements
    const int A = in_sizes[1] / (4 * B);     // 64
    const int N = in_sizes[0] / (4 * B);     // 65536

    const int nwPerBatch = N / 64;
    const bool pow2 = (nwPerBatch & (nwPerBatch - 1)) == 0;
    if (B == 8 && A <= MAX_A && (N % 64) == 0 && pow2) {
        dim3 block(256, 1, 1);
        dim3 grid(2 * nwPerBatch, 1, 1);     // 2048 blocks, 4 waves each
        assign_cls_b8<<<grid, block, 0, stream>>>(bbox, gt, gt_counts, counts,
                                                  out, N, A, nwPerBatch - 1);
    } else {
        dim3 block(256, 1, 1);
        dim3 grid((N + 255) / 256, B, 1);
        assign_cls_generic<<<grid, block, 0, stream>>>(bbox, gt, gt_counts,
                                                       counts, out, N, A);
    }
}

// Round 6
// 18.850 us; speedup vs baseline: 1.7489x; 1.0163x over previous
//
#include <hip/hip_runtime.h>

#define MAX_A 64

// Exact divisionless IoU threshold test:
//   RN(inter/uni) >= 0.7f  <=>  signbit(uni) ? inter < m*uni : inter > m*uni
// where m = 0x1.666665p-1 (the real-number rounding boundary: midpoint of
// [pred(0.7f), 0.7f]; pred has even mantissa so the tie rounds DOWN => strict >).
// (double)inter, (double)uni, and m*(double)uni (25b x 24b <= 53b) are all
// EXACT in f64, and f64 compare is exact => bit-identical to the f32 divide.
// signbit branch also covers uni == +-0 (inf/NaN quotient cases) exactly.
#define IOU_M 0x1.666665p-1

__global__ __launch_bounds__(256) void assign_cls_b8(
    const float4* __restrict__ bbox,      // [B, N]
    const float4* __restrict__ gt,        // [B, A]
    const int*    __restrict__ gt_counts, // [B]
    const int*    __restrict__ counts,    // [B]
    int*          __restrict__ out,       // [B, N]
    int N, int A, int nwMask)             // nwMask = N/64 - 1 (pow2)
{
    const int lane = threadIdx.x & 63;
    const int w    = threadIdx.x >> 6;          // wave in block: 0..3
    const int half = blockIdx.x & 1;            // which 4 batches
    const int b    = half * 4 + w;
    const int q    = blockIdx.x >> 1;           // 0..N/64-1
    const int nw   = (q * 421) & nwMask;        // bijective scramble (balance)
    const int n    = nw * 64 + lane;

    __shared__ float4 sgt[4][MAX_A];
    __shared__ float  sga[4][MAX_A];
    for (int i = threadIdx.x; i < 4 * A; i += 256) {
        const int lb = i / A, a = i - lb * A;
        float4 g = gt[(size_t)(half * 4 + lb) * A + a];
        sgt[lb][a] = g;
        sga[lb][a] = (g.z - g.x) * (g.w - g.y);   // ga
    }
    __syncthreads();

    const int cnt = counts[b];                  // wave-uniform
    const int G   = min(gt_counts[b], A);       // wave-uniform

    int label = 0;
    if (n < cnt) {
        const float4 bb = bbox[(size_t)b * N + n];   // coalesced dwordx4
        const float area = (bb.z - bb.x) * (bb.w - bb.y);

        #pragma unroll 4
        for (int g = 0; g < G; ++g) {
            const float4 gb = sgt[w][g];             // uniform addr: broadcast
            const float yy1 = fminf(fmaxf(bb.x, gb.x), gb.z);
            const float xx1 = fminf(fmaxf(bb.y, gb.y), gb.w);
            const float yy2 = fminf(fmaxf(bb.z, gb.x), gb.z);
            const float xx2 = fminf(fmaxf(bb.w, gb.y), gb.w);
            const float inter = (yy2 - yy1) * (xx2 - xx1);
            const float uni   = (area + sga[w][g]) - inter;
            const double mu = IOU_M * (double)uni;   // exact
            const double di = (double)inter;         // exact
            label |= (__float_as_int(uni) < 0) ? (di < mu) : (di > mu);
        }
    }
    out[(size_t)b * N + n] = label;
}

// Generic fallback (any B/A/N), same divisionless compare.
__global__ __launch_bounds__(256) void assign_cls_generic(
    const float4* __restrict__ bbox, const float4* __restrict__ gt,
    const int* __restrict__ gt_counts, const int* __restrict__ counts,
    int* __restrict__ out, int N, int A)
{
    const int b = blockIdx.y;
    const int n = blockIdx.x * blockDim.x + threadIdx.x;
    if (n >= N) return;
    const int cnt = counts[b];
    const int G   = min(gt_counts[b], A);
    int label = 0;
    if (n < cnt) {
        const float4 bb = bbox[(size_t)b * N + n];
        const float area = (bb.z - bb.x) * (bb.w - bb.y);
        for (int g = 0; g < G; ++g) {
            const float4 gb = gt[(size_t)b * A + g];
            const float ga = (gb.z - gb.x) * (gb.w - gb.y);
            const float yy1 = fminf(fmaxf(bb.x, gb.x), gb.z);
            const float xx1 = fminf(fmaxf(bb.y, gb.y), gb.w);
            const float yy2 = fminf(fmaxf(bb.z, gb.x), gb.z);
            const float xx2 = fminf(fmaxf(bb.w, gb.y), gb.w);
            const float inter = (yy2 - yy1) * (xx2 - xx1);
            const float uni   = (area + ga) - inter;
            const double mu = IOU_M * (double)uni;
            const double di = (double)inter;
            label |= (__float_as_int(uni) < 0) ? (di < mu) : (di > mu);
        }
    }
    out[(size_t)b * N + n] = label;
}

extern "C" void kernel_launch(void* const* d_in, const int* in_sizes, int n_in,
                              void* d_out, int out_size, void* d_ws, size_t ws_size,
                              hipStream_t stream) {
    const float4* bbox      = (const float4*)d_in[0];
    const float4* gt        = (const float4*)d_in[1];
    const int*    gt_counts = (const int*)d_in[2];
    const int*    counts    = (const int*)d_in[3];
    int*          out       = (int*)d_out;

    const int B = in_sizes[2];               // gt_counts has B elements
    const int A = in_sizes[1] / (4 * B);     // 64
    const int N = in_sizes[0] / (4 * B);     // 65536

    const int nwPerBatch = N / 64;
    const bool pow2 = (nwPerBatch & (nwPerBatch - 1)) == 0;
    if (B == 8 && A <= MAX_A && (N % 64) == 0 && pow2) {
        dim3 block(256, 1, 1);
        dim3 grid(2 * nwPerBatch, 1, 1);     // 2048 blocks, 4 waves each
        assign_cls_b8<<<grid, block, 0, stream>>>(bbox, gt, gt_counts, counts,
                                                  out, N, A, nwPerBatch - 1);
    } else {
        dim3 block(256, 1, 1);
        dim3 grid((N + 255) / 256, B, 1);
        assign_cls_generic<<<grid, block, 0, stream>>>(bbox, gt, gt_counts,
                                                       counts, out, N, A);
    }
}